// Round 5
// baseline (976.631 us; speedup 1.0000x reference)
//
#include <hip/hip_runtime.h>
#include <stdint.h>

// ---------------------------------------------------------------------------
// B=256, H=W=14, HW=196, TS=0.03, TC=0.07, TP_K=19, TN_K=98
// Conv inputs live in a padded 16x16 cell grid per image (1-cell zero halo):
// cell = b*256 + (h+1)*16 + (w+1). Conv 3x3 = 9 cell-row shifts delta=dh*16+dw.
// Logical conv M-space is w-PADDED to 16 slots/image-row: lr = b*224 + h*16 + ws
// (ws<14 valid). cell(lr) = lr + 32*(lr/224) + 17 -> 16 consecutive lr are
// cell-consecutive except +33 jumps; 33 % 8 == 1 so bank residues stay
// balanced. LDS rows use stride 72 shorts (144 B = 36 words = 4 mod 32):
// 16 consecutive rows cover every bank exactly 2x -> conflict-free WITHOUT
// any XOR swizzle, and staging is a linear DMA from k-major global layouts
// [kc][row][64 data + 8 pad shorts] (pad seg never read by fragments).
// Per kc: stage ONE 256-row A window (covers all 9 taps; span<=194) and run
// the 9 taps against it with B (weights) double-buffered per tap.
// NOTE (R3 bug): workspace regions are reused; size each by the MAX of its
// occupants or buffers alias and later GEMMs read bytes being written.
// ---------------------------------------------------------------------------

typedef __attribute__((ext_vector_type(8))) short bf16x8;
typedef __attribute__((ext_vector_type(4))) float f32x4;

__device__ __forceinline__ unsigned short f2bf(float x) {
  unsigned u = __float_as_uint(x);
  unsigned r = u + 0x7FFFu + ((u >> 16) & 1u);  // RNE, no NaNs here
  return (unsigned short)(r >> 16);
}
__device__ __forceinline__ float bf2f(unsigned short h) {
  return __uint_as_float(((unsigned)h) << 16);
}

typedef const __attribute__((address_space(1))) void* gptr1_t;
typedef __attribute__((address_space(3))) void* lptr3_t;
__device__ __forceinline__ void gload_lds16(const void* g, void* l) {
  __builtin_amdgcn_global_load_lds((gptr1_t)g, (lptr3_t)l, 16, 0, 0);
}

__device__ __forceinline__ float waveSum(float v) {
#pragma unroll
  for (int m = 1; m < 64; m <<= 1) v += __shfl_xor(v, m, 64);
  return v;
}
__device__ __forceinline__ float waveMax(float v) {
#pragma unroll
  for (int m = 1; m < 64; m <<= 1) v = fmaxf(v, __shfl_xor(v, m, 64));
  return v;
}
template <int NW>
__device__ __forceinline__ float blockSum(float v) {
  __shared__ float sh[NW];
  v = waveSum(v);
  int wv = threadIdx.x >> 6, ln = threadIdx.x & 63;
  if (ln == 0) sh[wv] = v;
  __syncthreads();
  float r = 0.f;
#pragma unroll
  for (int w = 0; w < NW; ++w) r += sh[w];
  __syncthreads();
  return r;
}
template <int NW>
__device__ __forceinline__ float blockMax(float v) {
  __shared__ float sh[NW];
  v = waveMax(v);
  int wv = threadIdx.x >> 6, ln = threadIdx.x & 63;
  if (ln == 0) sh[wv] = v;
  __syncthreads();
  float r = -3.4e38f;
#pragma unroll
  for (int w = 0; w < NW; ++w) r = fmaxf(r, sh[w]);
  __syncthreads();
  return r;
}

#define RA 65552  // rows per k-slice of conv input buffers (65536 + guard)

// ---------------------------------------------------------------------------
// convtap3_k: C[lr,n] = sum_t sum_k A[cell(lr)+d_t, k] * B[t,n,k]
// Block 128(lr) x 128(n), 256 thr, 4 waves (2x2), wave-tile 64x64 (4x4 frags
// of 16x16x32). A: [kc][RA][72] shorts; B: [t][kc][512][72]. LDS: A window
// 256x72 (36 KB) + B dbuf 2x128x72 (36 KB) = 72 KB -> 2 blocks/CU.
// EPI 0: relu -> x1b (cell rows, k-major slices). EPI 1: bf16 -> fv compact.
// ---------------------------------------------------------------------------
template <int KC, int EPI>
__global__ __launch_bounds__(256, 2) void convtap3_k(
    const unsigned short* __restrict__ A, const unsigned short* __restrict__ Bw,
    unsigned short* __restrict__ C) {
  __shared__ short Ah[256 * 72];
  __shared__ short Bb[2][128 * 72];
  const int tid = threadIdx.x;
  const int wave = tid >> 6, lane = tid & 63;
  const int wm = wave >> 1, wn = wave & 1;
  const int quad = lane >> 4, tq = lane & 15;
  const int m0 = blockIdx.x * 128, n0 = blockIdx.y * 128;
  const int base = m0 + 32 * (m0 / 224);  // cell(m0) - 17

  int pab[4];
#pragma unroll
  for (int mi = 0; mi < 4; ++mi) {
    int lr = m0 + wm * 64 + mi * 16 + tq;
    int cell = lr + 32 * (lr / 224) + 17;
    pab[mi] = (cell - base) * 72 + quad * 8;  // cell-base in [17,176]
  }
  int nb[4];
#pragma unroll
  for (int ni = 0; ni < 4; ++ni)
    nb[ni] = (wn * 64 + ni * 16 + tq) * 72 + quad * 8;

  const char* Abase = (const char*)A;
  const char* Bbase = (const char*)Bw;
  const size_t amax = (size_t)KC * RA * 144 - 1024;
  const int l16 = lane * 16;

  f32x4 acc[4][4];
#pragma unroll
  for (int mi = 0; mi < 4; ++mi)
#pragma unroll
    for (int ni = 0; ni < 4; ++ni) {
      f32x4 z = {0.f, 0.f, 0.f, 0.f};
      acc[mi][ni] = z;
    }

#pragma unroll 1
  for (int kc = 0; kc < KC; ++kc) {
    __syncthreads();
    {  // A window: 36 KB linear (clamped tail chunks feed dead rows only)
      size_t s0 = ((size_t)kc * RA + base) * 144;
#pragma unroll
      for (int i = 0; i < 9; ++i) {
        int c = i * 4 + wave;
        size_t s = s0 + (size_t)c * 1024;
        if (s > amax) s = amax;
        gload_lds16(Abase + s + l16, (char*)Ah + c * 1024);
      }
    }
    {  // B tap 0: 18 KB linear
      size_t s0 = ((size_t)kc * 512 + n0) * 144;
#pragma unroll
      for (int i = 0; i < 5; ++i) {
        int c = i * 4 + wave;
        if (c < 18)
          gload_lds16(Bbase + s0 + c * 1024 + l16, (char*)Bb[0] + c * 1024);
      }
    }
    __syncthreads();
#pragma unroll
    for (int t = 0; t < 9; ++t) {
      if (t < 8) {  // prefetch B(t+1) into the other buffer
        size_t s0 = ((size_t)((t + 1) * KC + kc) * 512 + n0) * 144;
#pragma unroll
        for (int i = 0; i < 5; ++i) {
          int c = i * 4 + wave;
          if (c < 18)
            gload_lds16(Bbase + s0 + c * 1024 + l16,
                        (char*)Bb[(t + 1) & 1] + c * 1024);
        }
      }
      const int aoff = (((t / 3) - 1) * 16 + (t % 3) - 1) * 72;
      const short* Bc = Bb[t & 1];
#pragma unroll
      for (int h = 0; h < 2; ++h) {
        bf16x8 af[4], bf[4];
#pragma unroll
        for (int mi = 0; mi < 4; ++mi)
          af[mi] = *(const bf16x8*)&Ah[pab[mi] + aoff + h * 32];
#pragma unroll
        for (int ni = 0; ni < 4; ++ni)
          bf[ni] = *(const bf16x8*)&Bc[nb[ni] + h * 32];
#pragma unroll
        for (int mi = 0; mi < 4; ++mi)
#pragma unroll
          for (int ni = 0; ni < 4; ++ni)
            acc[mi][ni] = __builtin_amdgcn_mfma_f32_16x16x32_bf16(
                af[mi], bf[ni], acc[mi][ni], 0, 0, 0);
      }
      if (t < 8) __syncthreads();
    }
  }

#pragma unroll
  for (int mi = 0; mi < 4; ++mi) {
#pragma unroll
    for (int r = 0; r < 4; ++r) {
      int lr = m0 + wm * 64 + mi * 16 + quad * 4 + r;
      int bb = lr / 224;
      int rem = lr - bb * 224;
      int ws = rem & 15;
      if (ws >= 14) continue;  // dead slot
      if (EPI == 0) {
        int cell = lr + 32 * bb + 17;
        int slice = (n0 >> 6) + wn;
        size_t ob = ((size_t)slice * RA + cell) * 72 + tq;
#pragma unroll
        for (int ni = 0; ni < 4; ++ni)
          C[ob + ni * 16] = f2bf(fmaxf(acc[mi][ni][r], 0.f));
      } else {
        int fr = bb * 196 + (rem >> 4) * 14 + ws;
        size_t ob = (size_t)fr * 512 + n0 + wn * 64 + tq;
#pragma unroll
        for (int ni = 0; ni < 4; ++ni)
          C[ob + ni * 16] = f2bf(acc[mi][ni][r]);
      }
    }
  }
}

// ---------------------------------------------------------------------------
// gemm1_k: plain C[m,n] = sum_k A[m,k]*B[n,k]; 128x128 tile, 4 waves, BK=64,
// XOR-swizzled LDS (contiguous rows -> conflict-free). EPI 0 relu->bf16, 2 f32.
// ---------------------------------------------------------------------------
template <int K, int NLD, int EPI>
__global__ __launch_bounds__(256, 2) void gemm1_k(
    const unsigned short* __restrict__ A, const unsigned short* __restrict__ Bw,
    void* __restrict__ C) {
  __shared__ short As[128 * 64];
  __shared__ short Bs[128 * 64];
  const int tid = threadIdx.x;
  const int wave = tid >> 6, lane = tid & 63;
  const int m0 = blockIdx.x * 128, n0 = blockIdx.y * 128;
  const int rr8 = lane >> 3, seg = lane & 7, gseg = seg ^ rr8;
  const int wm = wave >> 1, wn = wave & 1;
  const int quad = lane >> 4, tq = lane & 15;

  size_t asrc[4], bsrc[4];
#pragma unroll
  for (int i8 = 0; i8 < 4; ++i8) {
    int rloc = wave * 32 + i8 * 8 + rr8;
    asrc[i8] = (size_t)(m0 + rloc) * K + gseg * 8;
    bsrc[i8] = (size_t)(n0 + rloc) * K + gseg * 8;
  }

  f32x4 acc[4][4];
#pragma unroll
  for (int mi = 0; mi < 4; ++mi)
#pragma unroll
    for (int ni = 0; ni < 4; ++ni) {
      f32x4 z = {0.f, 0.f, 0.f, 0.f};
      acc[mi][ni] = z;
    }

#pragma unroll 1
  for (int kc2 = 0; kc2 < K / 64; ++kc2) {
    int kb = kc2 * 64;
    __syncthreads();
#pragma unroll
    for (int i8 = 0; i8 < 4; ++i8) {
      gload_lds16(A + asrc[i8] + kb, &As[(wave * 32 + i8 * 8) * 64]);
      gload_lds16(Bw + bsrc[i8] + kb, &Bs[(wave * 32 + i8 * 8) * 64]);
    }
    __syncthreads();
#pragma unroll
    for (int h = 0; h < 2; ++h) {
      bf16x8 af[4], bfr[4];
#pragma unroll
      for (int mi = 0; mi < 4; ++mi) {
        int row = wm * 64 + mi * 16 + tq;
        af[mi] = *(const bf16x8*)&As[row * 64 +
                                     ((((h << 2) | quad) ^ (row & 7)) << 3)];
      }
#pragma unroll
      for (int ni = 0; ni < 4; ++ni) {
        int row = wn * 64 + ni * 16 + tq;
        bfr[ni] = *(const bf16x8*)&Bs[row * 64 +
                                      ((((h << 2) | quad) ^ (row & 7)) << 3)];
      }
#pragma unroll
      for (int mi = 0; mi < 4; ++mi)
#pragma unroll
        for (int ni = 0; ni < 4; ++ni)
          acc[mi][ni] = __builtin_amdgcn_mfma_f32_16x16x32_bf16(
              af[mi], bfr[ni], acc[mi][ni], 0, 0, 0);
    }
  }

#pragma unroll
  for (int mi = 0; mi < 4; ++mi) {
#pragma unroll
    for (int r = 0; r < 4; ++r) {
      int m = m0 + wm * 64 + mi * 16 + quad * 4 + r;
      size_t obase = (size_t)m * NLD + n0 + wn * 64 + tq;
#pragma unroll
      for (int ni = 0; ni < 4; ++ni) {
        float v = acc[mi][ni][r];
        size_t idx = obase + ni * 16;
        if (EPI == 0)
          ((unsigned short*)C)[idx] = f2bf(fmaxf(v, 0.f));
        else
          ((float*)C)[idx] = v;
      }
    }
  }
}

// Xm = (iv+eps).fa^T and Vm = indn.indn^T in one dispatch (blockIdx.z picks)
__global__ __launch_bounds__(256, 2) void gemm_xv_k(
    const unsigned short* __restrict__ ivpb, const unsigned short* __restrict__ fab,
    const unsigned short* __restrict__ indnb, float* __restrict__ Xm,
    float* __restrict__ Vm) {
  const unsigned short* A = blockIdx.z ? indnb : ivpb;
  const unsigned short* Bw = blockIdx.z ? indnb : fab;
  float* C = blockIdx.z ? Vm : Xm;
  __shared__ short As[128 * 64];
  __shared__ short Bs[128 * 64];
  const int tid = threadIdx.x;
  const int wave = tid >> 6, lane = tid & 63;
  const int m0 = blockIdx.x * 128, n0 = blockIdx.y * 128;
  const int rr8 = lane >> 3, seg = lane & 7, gseg = seg ^ rr8;
  const int wm = wave >> 1, wn = wave & 1;
  const int quad = lane >> 4, tq = lane & 15;
  size_t asrc[4], bsrc[4];
#pragma unroll
  for (int i8 = 0; i8 < 4; ++i8) {
    int rloc = wave * 32 + i8 * 8 + rr8;
    asrc[i8] = (size_t)(m0 + rloc) * 512 + gseg * 8;
    bsrc[i8] = (size_t)(n0 + rloc) * 512 + gseg * 8;
  }
  f32x4 acc[4][4];
#pragma unroll
  for (int mi = 0; mi < 4; ++mi)
#pragma unroll
    for (int ni = 0; ni < 4; ++ni) {
      f32x4 z = {0.f, 0.f, 0.f, 0.f};
      acc[mi][ni] = z;
    }
#pragma unroll 1
  for (int kc2 = 0; kc2 < 8; ++kc2) {
    int kb = kc2 * 64;
    __syncthreads();
#pragma unroll
    for (int i8 = 0; i8 < 4; ++i8) {
      gload_lds16(A + asrc[i8] + kb, &As[(wave * 32 + i8 * 8) * 64]);
      gload_lds16(Bw + bsrc[i8] + kb, &Bs[(wave * 32 + i8 * 8) * 64]);
    }
    __syncthreads();
#pragma unroll
    for (int h = 0; h < 2; ++h) {
      bf16x8 af[4], bfr[4];
#pragma unroll
      for (int mi = 0; mi < 4; ++mi) {
        int row = wm * 64 + mi * 16 + tq;
        af[mi] = *(const bf16x8*)&As[row * 64 +
                                     ((((h << 2) | quad) ^ (row & 7)) << 3)];
      }
#pragma unroll
      for (int ni = 0; ni < 4; ++ni) {
        int row = wn * 64 + ni * 16 + tq;
        bfr[ni] = *(const bf16x8*)&Bs[row * 64 +
                                      ((((h << 2) | quad) ^ (row & 7)) << 3)];
      }
#pragma unroll
      for (int mi = 0; mi < 4; ++mi)
#pragma unroll
        for (int ni = 0; ni < 4; ++ni)
          acc[mi][ni] = __builtin_amdgcn_mfma_f32_16x16x32_bf16(
              af[mi], bfr[ni], acc[mi][ni], 0, 0, 0);
    }
  }
#pragma unroll
  for (int mi = 0; mi < 4; ++mi)
#pragma unroll
    for (int r = 0; r < 4; ++r) {
      int m = m0 + wm * 64 + mi * 16 + quad * 4 + r;
      size_t obase = (size_t)m * 256 + n0 + wn * 64 + tq;
#pragma unroll
      for (int ni = 0; ni < 4; ++ni) C[obase + ni * 16] = acc[mi][ni][r];
    }
}

// --------------------------- prep (fused) ----------------------------------
// ranges: ea/Wf1/Wf2 casts | wb1 build | wb2 build | x1b halo+guard zeroing
__global__ void prep_all_k(const float* __restrict__ ea,
                           const float* __restrict__ Wf1,
                           const float* __restrict__ Wf2,
                           const float* __restrict__ Wc1,
                           const float* __restrict__ Wc2,
                           unsigned short* __restrict__ eab,
                           unsigned short* __restrict__ wf1b,
                           unsigned short* __restrict__ wf2b,
                           unsigned short* __restrict__ wb1,
                           unsigned short* __restrict__ wb2,
                           unsigned int* __restrict__ x1u) {
  int i = blockIdx.x * 256 + threadIdx.x;
  if (i < 524288) {
    eab[i] = f2bf(ea[i]);
  } else if (i < 1572864) {
    int j = i - 524288;
    wf1b[j] = f2bf(Wf1[j]);
  } else if (i < 1835008) {
    int j = i - 1572864;
    wf2b[j] = f2bf(Wf2[j]);
  } else if (i < 3604480) {
    int j = i - 1835008;  // wb1: [t][kc6][n][72] <- Wc1[n][384][3][3]
    int t = j / (6 * 512 * 64), r = j - t * (6 * 512 * 64);
    int kc = r / (512 * 64), r2 = r - kc * (512 * 64);
    int n = r2 >> 6, c = r2 & 63;
    wb1[((size_t)(t * 6 + kc) * 512 + n) * 72 + c] =
        f2bf(Wc1[(n * 384 + kc * 64 + c) * 9 + t]);
  } else if (i < 5963776) {
    int j = i - 3604480;  // wb2: [t][kc8][n][72] <- Wc2[n][512][3][3]
    int t = j / (8 * 512 * 64), r = j - t * (8 * 512 * 64);
    int kc = r / (512 * 64), r2 = r - kc * (512 * 64);
    int n = r2 >> 6, c = r2 & 63;
    wb2[((size_t)(t * 8 + kc) * 512 + n) * 72 + c] =
        f2bf(Wc2[(n * 512 + kc * 64 + c) * 9 + t]);
  } else {
    int j = i - 5963776;  // 15360 halo rows x 8 slices x 32 uints
    int hr = j >> 8, u = j & 255;
    int slice = u >> 5, uu = u & 31;
    int b = hr / 60, c = hr - b * 60;
    int cell;
    if (c < 16) cell = c;
    else if (c < 32) cell = 240 + (c - 16);
    else if (c < 46) cell = (c - 31) * 16;
    else cell = (c - 45) * 16 + 15;
    x1u[((size_t)slice * RA + b * 256 + cell) * 36 + uu] = 0u;
  }
}

// ev (256,384,14,14) fp32 -> evb [kc6][RA][72] bf16 (halo rows zero)
__global__ __launch_bounds__(256) void evpad_k(const float* __restrict__ ev,
                                               unsigned short* __restrict__ out) {
  int b = blockIdx.x, ct = blockIdx.y;  // channel tile: c0 = ct*64
  __shared__ float tile[64][197];
  int tid = threadIdx.x;
  const float* src = ev + ((size_t)b * 384 + ct * 64) * 196;
#pragma unroll 1
  for (int it = 0; it < 49; ++it) {
    int idx = it * 256 + tid;
    int c = idx / 196, p = idx - c * 196;
    tile[c][p] = src[idx];
  }
  __syncthreads();
  unsigned short* dst = out + ((size_t)ct * RA + b * 256) * 72;
#pragma unroll 1
  for (int it = 0; it < 64; ++it) {
    int idx = it * 256 + tid;
    int cell = idx >> 6, c = idx & 63;
    int h = (cell >> 4) - 1, w = (cell & 15) - 1;
    float v = ((unsigned)h < 14u && (unsigned)w < 14u) ? tile[c][h * 14 + w]
                                                       : 0.f;
    dst[(size_t)cell * 72 + c] = f2bf(v);
  }
}

// --------------------------- pooling / norms -------------------------------

__global__ __launch_bounds__(512) void pool_k(
    const unsigned short* __restrict__ fv, const int* __restrict__ masks,
    float* __restrict__ indv, float* __restrict__ rn) {
  int b = blockIdx.x;
  int w = threadIdx.x >> 6, lane = threadIdx.x & 63;
  __shared__ float red[8][512];
  __shared__ float msh[8];
  float acc[8] = {0.f, 0.f, 0.f, 0.f, 0.f, 0.f, 0.f, 0.f};
  float msum = 0.f;
  for (int p = w; p < 196; p += 8) {
    float m = (float)masks[b * 196 + p];
    msum += m;
    uint4 d = *(const uint4*)(fv + (size_t)(b * 196 + p) * 512 + lane * 8);
    const unsigned short* hp = (const unsigned short*)&d;
    float ss = 0.f;
#pragma unroll
    for (int k = 0; k < 8; ++k) {
      float x = bf2f(hp[k]);
      ss += x * x;
      acc[k] += m * x;
    }
    ss = waveSum(ss);
    if (lane == 0) rn[b * 196 + p] = 1.f / fmaxf(sqrtf(ss), 1e-12f);
  }
#pragma unroll
  for (int k = 0; k < 8; ++k) red[w][lane * 8 + k] = acc[k];
  if (lane == 0) msh[w] = msum;
  __syncthreads();
  int tid = threadIdx.x;
  float s = 0.f, mtot = 0.f;
#pragma unroll
  for (int ww = 0; ww < 8; ++ww) {
    s += red[ww][tid];
    mtot += msh[ww];
  }
  indv[b * 512 + tid] = s / mtot;
}

// b<256: indn + ivpb + Pi ; b>=256: fab + Qj
__global__ __launch_bounds__(512) void norms_k(
    const float* __restrict__ indv, const float* __restrict__ fa,
    float* __restrict__ indn, unsigned short* __restrict__ indnb,
    unsigned short* __restrict__ ivpb, float* __restrict__ Pi,
    unsigned short* __restrict__ fab, float* __restrict__ Qj) {
  int b = blockIdx.x, tid = threadIdx.x;
  if (b < 256) {
    float v = indv[b * 512 + tid];
    float ss = blockSum<8>(v * v);
    float sc = 1.f / fmaxf(sqrtf(ss), 1e-12f);
    float o = v * sc;
    indn[b * 512 + tid] = o;
    indnb[b * 512 + tid] = f2bf(o);
    float ve = v + 1e-6f;
    ivpb[b * 512 + tid] = f2bf(ve);
    float p2 = blockSum<8>(ve * ve);
    if (tid == 0) Pi[b] = p2;
  } else {
    b -= 256;
    float v = fa[b * 512 + tid];
    fab[b * 512 + tid] = f2bf(v);
    float q = blockSum<8>(v * v);
    if (tid == 0) Qj[b] = q;
  }
}

// ------------------------------ SP / SN ------------------------------------

__device__ __forceinline__ float radix_kth(unsigned k0, unsigned k1, unsigned k2,
                                           unsigned k3, int k) {
  unsigned prefix = 0;
  int kk = k;
#pragma unroll 1
  for (int bit = 31; bit >= 14; --bit) {  // 18 steps; thr err ~2^-9 rel, ok
    unsigned thi = (prefix >> bit) | 1u;
    int c = __popcll(__ballot((k0 >> bit) == thi)) +
            __popcll(__ballot((k1 >> bit) == thi)) +
            __popcll(__ballot((k2 >> bit) == thi)) +
            __popcll(__ballot((k3 >> bit) == thi));
    if (kk <= c)
      prefix |= (1u << bit);
    else
      kk -= c;
  }
  unsigned u = (prefix & 0x80000000u) ? (prefix ^ 0x80000000u) : ~prefix;
  return __uint_as_float(u);
}
__device__ __forceinline__ unsigned sortkey(float x) {
  unsigned u = __float_as_uint(x);
  return u ^ (((int)u >> 31) | 0x80000000u);
}

__global__ __launch_bounds__(256) void spsn_k(const float* __restrict__ Sij,
                                              const float* __restrict__ rn,
                                              float* __restrict__ SP,
                                              float* __restrict__ SN) {
  int i = blockIdx.x, jg = blockIdx.y;
  int tid = threadIdx.x, wave = tid >> 6, lane = tid & 63;
  __shared__ float tile[196 * 65];
#pragma unroll 1
  for (int it = 0; it < 49; ++it) {
    int lin = it * 256 + tid;
    int p = lin >> 6, j = lin & 63;
    tile[p * 65 + j] =
        Sij[(size_t)(i * 196 + p) * 256 + jg * 64 + j] * rn[i * 196 + p];
  }
  __syncthreads();
#pragma unroll 1
  for (int jj = 0; jj < 16; ++jj) {
    int j = jj * 4 + wave;
    float v0 = tile[lane * 65 + j];
    float v1 = tile[(lane + 64) * 65 + j];
    float v2 = tile[(lane + 128) * 65 + j];
    bool val3 = lane < 4;
    float v3 = val3 ? tile[(lane + 192) * 65 + j] : 0.f;
    unsigned k0 = sortkey(v0), k1 = sortkey(v1), k2 = sortkey(v2);
    unsigned k3 = val3 ? sortkey(v3) : 0u;
    float thrP = radix_kth(k0, k1, k2, k3, 19);
    float thrN = radix_kth(k0, k1, k2, k3, 99);
    float spn = 0.f, spd = 0.f, snn = 0.f, snd = 0.f;
    const float invTS = 1.f / 0.03f;
#pragma unroll
    for (int q = 0; q < 4; ++q) {
      float v = (q == 0) ? v0 : (q == 1) ? v1 : (q == 2) ? v2 : v3;
      bool ok = (q < 3) || val3;
      if (ok) {
        float mp = 1.f / (1.f + __expf((thrP - v) * invTS));
        float mn = 1.f / (1.f + __expf((v - thrN) * invTS));
        spn += v * mp;
        spd += mp;
        snn += v * mn;
        snd += mn;
      }
    }
    spn = waveSum(spn); spd = waveSum(spd);
    snn = waveSum(snn); snd = waveSum(snd);
    if (lane == 0) {
      SP[i * 256 + jg * 64 + j] = spn / spd;
      SN[i * 256 + jg * 64 + j] = snn / snd;
    }
  }
}

__global__ __launch_bounds__(256) void loss12_k(const float* __restrict__ SP,
                                                const float* __restrict__ SN,
                                                float* __restrict__ out) {
  int r = blockIdx.x;
  int i = r & 255;
  bool col = r >= 256;
  int tid = threadIdx.x;
  const float invTC = 1.f / 0.07f;
  float a = (col ? SP[tid * 256 + i] : SP[i * 256 + tid]) * invTC;
  float b = (col ? SN[tid * 256 + i] : SN[i * 256 + tid]) * invTC;
  float mx = blockMax<4>(fmaxf(a, b));
  float se = blockSum<4>(__expf(a - mx) + __expf(b - mx));
  float lse = mx + __logf(se);
  if (tid == 0) {
    float diag = SP[i * 256 + i] * invTC;
    atomicAdd(out, -(diag - lse) * (1.f / 512.f));
  }
}

__global__ __launch_bounds__(256) void distcomb_k(
    const float* __restrict__ Pi, const float* __restrict__ Qj,
    const float* __restrict__ X, const float* __restrict__ V,
    float* __restrict__ val, float* __restrict__ out) {
  int i = blockIdx.x, j = threadIdx.x;
  float d = Pi[i] - 2.f * X[i * 256 + j] + Qj[j];
  float w = (i == j) ? 1.f : -V[i * 256 + j];
  float x = d * w;
  val[i * 256 + j] = x;
  __shared__ float diag_sh;
  if (j == i) diag_sh = x;
  float tot = blockSum<4>(x);
  if (j == 0) {
    float rs = diag_sh - (tot - diag_sh) * (1.f / 255.f);
    atomicAdd(out + 1, fmaxf(rs + 0.6f, 0.f) * (1.f / 512.f));
  }
}

__global__ __launch_bounds__(256) void loss4_k(const float* __restrict__ val,
                                               float* __restrict__ out) {
  int j = blockIdx.x, i = threadIdx.x;
  float x = val[i * 256 + j];
  __shared__ float diag_sh;
  if (i == j) diag_sh = x;
  float tot = blockSum<4>(x);
  if (i == 0) {
    float cs = diag_sh - (tot - diag_sh) * (1.f / 255.f);
    atomicAdd(out + 1, fmaxf(cs + 0.6f, 0.f) * (1.f / 512.f));
  }
}

// ---------------------------------------------------------------------------

extern "C" void kernel_launch(void* const* d_in, const int* in_sizes, int n_in,
                              void* d_out, int out_size, void* d_ws,
                              size_t ws_size, hipStream_t stream) {
  (void)in_sizes; (void)n_in; (void)out_size; (void)ws_size;
  const float* ev = (const float*)d_in[0];
  const float* ea = (const float*)d_in[1];
  const int* msk = (const int*)d_in[2];
  const float* Wf1 = (const float*)d_in[3];
  const float* Wf2 = (const float*)d_in[4];
  const float* Wc1 = (const float*)d_in[5];
  const float* Wc2 = (const float*)d_in[6];
  float* out = (float*)d_out;
  char* ws = (char*)d_ws;

  size_t off = 0;
  auto alloc = [&](size_t bytes) {
    void* p = ws + off;
    off = (off + bytes + 255) & ~(size_t)255;
    return p;
  };
  // Region 1: max(evb 6*RA*144 = 56,636,928 ; fv 50176*512*2 = 51,380,224)
  unsigned short* evb = (unsigned short*)alloc((size_t)6 * RA * 144);
  unsigned short* fv = evb;  // reused after conv2
  // Region 2: max(x1b 8*RA*144 = 75,515,904 ; Sij 50176*256*4 = 51,380,224)
  unsigned short* x1b = (unsigned short*)alloc((size_t)8 * RA * 144);
  float* Sij = (float*)x1b;  // reused after conv2
  unsigned short* wb1 = (unsigned short*)alloc((size_t)9 * 6 * 512 * 144);
  unsigned short* wb2 = (unsigned short*)alloc((size_t)9 * 8 * 512 * 144);
  unsigned short* eab = (unsigned short*)alloc((size_t)256 * 2048 * 2);
  unsigned short* wf1b = (unsigned short*)alloc((size_t)512 * 2048 * 2);
  unsigned short* wf2b = (unsigned short*)alloc((size_t)512 * 512 * 2);
  unsigned short* hb = (unsigned short*)alloc((size_t)256 * 512 * 2);
  float* fa = (float*)alloc((size_t)256 * 512 * 4);
  float* indv = (float*)alloc((size_t)256 * 512 * 4);
  float* indn = (float*)alloc((size_t)256 * 512 * 4);
  unsigned short* indnb = (unsigned short*)alloc((size_t)256 * 512 * 2);
  unsigned short* ivpb = (unsigned short*)alloc((size_t)256 * 512 * 2);
  unsigned short* fab = (unsigned short*)alloc((size_t)256 * 512 * 2);
  float* Pi = (float*)alloc(256 * 4);
  float* Qj = (float*)alloc(256 * 4);
  float* Xm = (float*)alloc((size_t)256 * 256 * 4);
  float* Vm = (float*)alloc((size_t)256 * 256 * 4);
  float* rn = (float*)alloc((size_t)50176 * 4);
  float* SP = (float*)alloc((size_t)256 * 256 * 4);
  float* SN = (float*)alloc((size_t)256 * 256 * 4);
  float* val = (float*)alloc((size_t)256 * 256 * 4);

  hipMemsetAsync(out, 0, 2 * sizeof(float), stream);

  prep_all_k<<<38656, 256, 0, stream>>>(ea, Wf1, Wf2, Wc1, Wc2, eab, wf1b,
                                        wf2b, wb1, wb2, (unsigned int*)x1b);
  evpad_k<<<dim3(256, 6), 256, 0, stream>>>(ev, evb);

  // conv1: relu, cell rows k-major (M=57344 logical, N=512, K=9*384)
  convtap3_k<6, 0><<<dim3(448, 4), 256, 0, stream>>>(evb, wb1, x1b);
  // fc1 / fc2
  gemm1_k<2048, 512, 0><<<dim3(2, 4), 256, 0, stream>>>(eab, wf1b, hb);
  gemm1_k<512, 512, 2><<<dim3(2, 4), 256, 0, stream>>>(hb, wf2b, fa);
  // conv2: compact bf16 out (M=57344 logical, N=512, K=9*512)
  convtap3_k<8, 1><<<dim3(448, 4), 256, 0, stream>>>(x1b, wb2, fv);

  pool_k<<<256, 512, 0, stream>>>(fv, msk, indv, rn);
  norms_k<<<512, 512, 0, stream>>>(indv, fa, indn, indnb, ivpb, Pi, fab, Qj);

  // Sij_raw[(i,p), j] = <fv[i,p,:], indn[j,:]>  (M=50176, N=256, K=512)
  gemm1_k<512, 256, 2><<<dim3(392, 2), 256, 0, stream>>>(fv, indnb, Sij);
  gemm_xv_k<<<dim3(2, 2, 2), 256, 0, stream>>>(ivpb, fab, indnb, Xm, Vm);

  spsn_k<<<dim3(256, 4), 256, 0, stream>>>(Sij, rn, SP, SN);
  loss12_k<<<512, 256, 0, stream>>>(SP, SN, out);
  distcomb_k<<<256, 256, 0, stream>>>(Pi, Qj, Xm, Vm, val, out);
  loss4_k<<<256, 256, 0, stream>>>(val, out);
}

// Round 6
// 851.970 us; speedup vs baseline: 1.1463x; 1.1463x over previous
//
#include <hip/hip_runtime.h>
#include <stdint.h>

// ---------------------------------------------------------------------------
// B=256, H=W=14, HW=196, TS=0.03, TC=0.07, TP_K=19, TN_K=98
// Conv inputs: padded 16x16 cell grid per image (1-cell zero halo):
// cell = b*256 + (h+1)*16 + (w+1). Conv 3x3 = 9 cell-row shifts d=dh*16+dw.
// convtap6_k: block = ONE image (M padded 196->224 rows) x 128 N. The A
// window per kc is EXACTLY the image's 256 cell rows (36.9 KB) — covers all
// 9 taps incl. halo with no clamping, no cross-image span. acc 7x4/wave
// (LDS 402 B/MFMA vs 512 at 4x4 — LDS-pipe cap ~58%); B (weights, k-major
// [t][kc][n][72]) double-buffered per tap; stride-72 LDS rows (144 B = 4 mod
// 32 dwords) keep reads bank-balanced with zero per-read swizzle math.
// Grid 256x4 at 2 blocks/CU -> exactly 4 slots/CU, no tail quantization.
// NOTE: workspace regions are reused; size each by the MAX of its occupants.
// ---------------------------------------------------------------------------

typedef __attribute__((ext_vector_type(8))) short bf16x8;
typedef __attribute__((ext_vector_type(4))) float f32x4;

__device__ __forceinline__ unsigned short f2bf(float x) {
  unsigned u = __float_as_uint(x);
  unsigned r = u + 0x7FFFu + ((u >> 16) & 1u);  // RNE, no NaNs here
  return (unsigned short)(r >> 16);
}
__device__ __forceinline__ float bf2f(unsigned short h) {
  return __uint_as_float(((unsigned)h) << 16);
}

typedef const __attribute__((address_space(1))) void* gptr1_t;
typedef __attribute__((address_space(3))) void* lptr3_t;
__device__ __forceinline__ void gload_lds16(const void* g, void* l) {
  __builtin_amdgcn_global_load_lds((gptr1_t)g, (lptr3_t)l, 16, 0, 0);
}

__device__ __forceinline__ float waveSum(float v) {
#pragma unroll
  for (int m = 1; m < 64; m <<= 1) v += __shfl_xor(v, m, 64);
  return v;
}
__device__ __forceinline__ float waveMax(float v) {
#pragma unroll
  for (int m = 1; m < 64; m <<= 1) v = fmaxf(v, __shfl_xor(v, m, 64));
  return v;
}
template <int NW>
__device__ __forceinline__ float blockSum(float v) {
  __shared__ float sh[NW];
  v = waveSum(v);
  int wv = threadIdx.x >> 6, ln = threadIdx.x & 63;
  if (ln == 0) sh[wv] = v;
  __syncthreads();
  float r = 0.f;
#pragma unroll
  for (int w = 0; w < NW; ++w) r += sh[w];
  __syncthreads();
  return r;
}
template <int NW>
__device__ __forceinline__ float blockMax(float v) {
  __shared__ float sh[NW];
  v = waveMax(v);
  int wv = threadIdx.x >> 6, ln = threadIdx.x & 63;
  if (ln == 0) sh[wv] = v;
  __syncthreads();
  float r = -3.4e38f;
#pragma unroll
  for (int w = 0; w < NW; ++w) r = fmaxf(r, sh[w]);
  __syncthreads();
  return r;
}

#define RA 65536  // rows per k-slice of conv input buffers

// ---------------------------------------------------------------------------
// convtap6_k: one image per block-x. C[p,n] = sum_t sum_k A[cell(p)+d_t,k]B[t,n,k]
// 256 thr, 4 waves (wm in {0,1}: 112 rows, wn in {0,1}: 64 cols), acc 7x4 of
// 16x16x32 bf16 MFMA. A: [kc][RA][72] shorts; B: [t][kc][512][72].
// LDS: A window 256x72 (36.9 KB) + B dbuf 2x128x72 (36.9 KB) = 73.7 KB.
// EPI 0: relu -> x1b (cell rows, k-major slices). EPI 1: bf16 -> fv compact.
// ---------------------------------------------------------------------------
template <int KC, int EPI>
__global__ __launch_bounds__(256, 2) void convtap6_k(
    const unsigned short* __restrict__ A, const unsigned short* __restrict__ Bw,
    unsigned short* __restrict__ C) {
  __shared__ __align__(16) short Ah[256 * 72];
  __shared__ __align__(16) short Bb[2][128 * 72];
  const int tid = threadIdx.x;
  const int wave = tid >> 6, lane = tid & 63;
  const int wm = wave >> 1, wn = wave & 1;
  const int quad = lane >> 4, tq = lane & 15;
  const int img = blockIdx.x, n0 = blockIdx.y * 128;

  int pab[7];
#pragma unroll
  for (int mi = 0; mi < 7; ++mi) {
    int p = wm * 112 + mi * 16 + tq;  // 0..223
    int h = p / 14, w = p - h * 14;
    int pr = (p < 196) ? ((h + 1) * 16 + w + 1) : 17;  // dead rows -> row 17
    pab[mi] = pr * 72 + quad * 8;
  }
  int nb[4];
#pragma unroll
  for (int ni = 0; ni < 4; ++ni)
    nb[ni] = (wn * 64 + ni * 16 + tq) * 72 + quad * 8;

  const char* Ab = (const char*)A;
  const char* Bg = (const char*)Bw;
  const int l16 = lane * 16;

  f32x4 acc[7][4];
#pragma unroll
  for (int mi = 0; mi < 7; ++mi)
#pragma unroll
    for (int ni = 0; ni < 4; ++ni) {
      f32x4 z = {0.f, 0.f, 0.f, 0.f};
      acc[mi][ni] = z;
    }

  auto stageA = [&](int kc) {
    size_t s0 = ((size_t)kc * RA + img * 256) * 144;
#pragma unroll
    for (int i = 0; i < 9; ++i) {
      int c = wave + i * 4;  // 36 chunks of 1024 B
      gload_lds16(Ab + s0 + (size_t)c * 1024 + l16, (char*)Ah + c * 1024);
    }
  };
  auto stageB = [&](int t, int kc, int buf) {
    size_t s0 = ((size_t)(t * KC + kc) * 512 + n0) * 144;
#pragma unroll
    for (int i = 0; i < 5; ++i) {
      int c = wave + i * 4;  // 18 chunks
      if (c < 18)
        gload_lds16(Bg + s0 + (size_t)c * 1024 + l16, (char*)Bb[buf] + c * 1024);
    }
  };

  stageA(0);
  stageB(0, 0, 0);
  __syncthreads();

  const int NS = KC * 9;
#pragma unroll 1
  for (int s = 0; s < NS; ++s) {
    int kc = s / 9, t = s - kc * 9;
    if (s + 1 < NS) {
      int kc1 = (s + 1) / 9, t1 = (s + 1) - kc1 * 9;
      stageB(t1, kc1, (s + 1) & 1);
    }
    const int aoff = (((t / 3) - 1) * 16 + (t % 3) - 1) * 72;
    const short* Bc = Bb[s & 1];
#pragma unroll
    for (int h = 0; h < 2; ++h) {
      bf16x8 af[7], bf[4];
#pragma unroll
      for (int mi = 0; mi < 7; ++mi)
        af[mi] = *(const bf16x8*)&Ah[pab[mi] + aoff + h * 32];
#pragma unroll
      for (int ni = 0; ni < 4; ++ni)
        bf[ni] = *(const bf16x8*)&Bc[nb[ni] + h * 32];
#pragma unroll
      for (int mi = 0; mi < 7; ++mi)
#pragma unroll
        for (int ni = 0; ni < 4; ++ni)
          acc[mi][ni] = __builtin_amdgcn_mfma_f32_16x16x32_bf16(
              af[mi], bf[ni], acc[mi][ni], 0, 0, 0);
    }
    __syncthreads();
    if (t == 8 && kc + 1 < KC) {
      stageA(kc + 1);
      __syncthreads();
    }
  }

#pragma unroll
  for (int mi = 0; mi < 7; ++mi) {
#pragma unroll
    for (int r = 0; r < 4; ++r) {
      int p = wm * 112 + mi * 16 + quad * 4 + r;
      if (p >= 196) continue;  // dead slot
      int h = p / 14, w = p - h * 14;
      if (EPI == 0) {
        int cell = img * 256 + (h + 1) * 16 + w + 1;
        int slice = (n0 >> 6) + wn;
        size_t ob = ((size_t)slice * RA + cell) * 72 + tq;
#pragma unroll
        for (int ni = 0; ni < 4; ++ni)
          C[ob + ni * 16] = f2bf(fmaxf(acc[mi][ni][r], 0.f));
      } else {
        size_t ob = (size_t)(img * 196 + p) * 512 + n0 + wn * 64 + tq;
#pragma unroll
        for (int ni = 0; ni < 4; ++ni)
          C[ob + ni * 16] = f2bf(acc[mi][ni][r]);
      }
    }
  }
}

// ---------------------------------------------------------------------------
// gemm1_k: C[m,n] = sum_k A[m,k]*B[n,k]; 128x128 tile, 4 waves, BK=64,
// XOR-swizzled LDS. EPI: 0 relu->bf16, 2 f32, 3 f32 * rs[m] (row scale).
// ---------------------------------------------------------------------------
template <int K, int NLD, int EPI>
__global__ __launch_bounds__(256, 2) void gemm1_k(
    const unsigned short* __restrict__ A, const unsigned short* __restrict__ Bw,
    void* __restrict__ C, const float* __restrict__ rs) {
  __shared__ short As[128 * 64];
  __shared__ short Bs[128 * 64];
  const int tid = threadIdx.x;
  const int wave = tid >> 6, lane = tid & 63;
  const int m0 = blockIdx.x * 128, n0 = blockIdx.y * 128;
  const int rr8 = lane >> 3, seg = lane & 7, gseg = seg ^ rr8;
  const int wm = wave >> 1, wn = wave & 1;
  const int quad = lane >> 4, tq = lane & 15;

  size_t asrc[4], bsrc[4];
#pragma unroll
  for (int i8 = 0; i8 < 4; ++i8) {
    int rloc = wave * 32 + i8 * 8 + rr8;
    asrc[i8] = (size_t)(m0 + rloc) * K + gseg * 8;
    bsrc[i8] = (size_t)(n0 + rloc) * K + gseg * 8;
  }

  f32x4 acc[4][4];
#pragma unroll
  for (int mi = 0; mi < 4; ++mi)
#pragma unroll
    for (int ni = 0; ni < 4; ++ni) {
      f32x4 z = {0.f, 0.f, 0.f, 0.f};
      acc[mi][ni] = z;
    }

#pragma unroll 1
  for (int kc2 = 0; kc2 < K / 64; ++kc2) {
    int kb = kc2 * 64;
    __syncthreads();
#pragma unroll
    for (int i8 = 0; i8 < 4; ++i8) {
      gload_lds16(A + asrc[i8] + kb, &As[(wave * 32 + i8 * 8) * 64]);
      gload_lds16(Bw + bsrc[i8] + kb, &Bs[(wave * 32 + i8 * 8) * 64]);
    }
    __syncthreads();
#pragma unroll
    for (int h = 0; h < 2; ++h) {
      bf16x8 af[4], bfr[4];
#pragma unroll
      for (int mi = 0; mi < 4; ++mi) {
        int row = wm * 64 + mi * 16 + tq;
        af[mi] = *(const bf16x8*)&As[row * 64 +
                                     ((((h << 2) | quad) ^ (row & 7)) << 3)];
      }
#pragma unroll
      for (int ni = 0; ni < 4; ++ni) {
        int row = wn * 64 + ni * 16 + tq;
        bfr[ni] = *(const bf16x8*)&Bs[row * 64 +
                                      ((((h << 2) | quad) ^ (row & 7)) << 3)];
      }
#pragma unroll
      for (int mi = 0; mi < 4; ++mi)
#pragma unroll
        for (int ni = 0; ni < 4; ++ni)
          acc[mi][ni] = __builtin_amdgcn_mfma_f32_16x16x32_bf16(
              af[mi], bfr[ni], acc[mi][ni], 0, 0, 0);
    }
  }

#pragma unroll
  for (int mi = 0; mi < 4; ++mi) {
#pragma unroll
    for (int r = 0; r < 4; ++r) {
      int m = m0 + wm * 64 + mi * 16 + quad * 4 + r;
      float sc = (EPI == 3) ? rs[m] : 1.f;
      size_t obase = (size_t)m * NLD + n0 + wn * 64 + tq;
#pragma unroll
      for (int ni = 0; ni < 4; ++ni) {
        float v = acc[mi][ni][r];
        size_t idx = obase + ni * 16;
        if (EPI == 0)
          ((unsigned short*)C)[idx] = f2bf(fmaxf(v, 0.f));
        else if (EPI == 2)
          ((float*)C)[idx] = v;
        else
          ((float*)C)[idx] = v * sc;
      }
    }
  }
}

// Xm = (iv+eps).fa^T and Vm = indn.indn^T in one dispatch (blockIdx.z picks)
__global__ __launch_bounds__(256, 2) void gemm_xv_k(
    const unsigned short* __restrict__ ivpb, const unsigned short* __restrict__ fab,
    const unsigned short* __restrict__ indnb, float* __restrict__ Xm,
    float* __restrict__ Vm) {
  const unsigned short* A = blockIdx.z ? indnb : ivpb;
  const unsigned short* Bw = blockIdx.z ? indnb : fab;
  float* C = blockIdx.z ? Vm : Xm;
  __shared__ short As[128 * 64];
  __shared__ short Bs[128 * 64];
  const int tid = threadIdx.x;
  const int wave = tid >> 6, lane = tid & 63;
  const int m0 = blockIdx.x * 128, n0 = blockIdx.y * 128;
  const int rr8 = lane >> 3, seg = lane & 7, gseg = seg ^ rr8;
  const int wm = wave >> 1, wn = wave & 1;
  const int quad = lane >> 4, tq = lane & 15;
  size_t asrc[4], bsrc[4];
#pragma unroll
  for (int i8 = 0; i8 < 4; ++i8) {
    int rloc = wave * 32 + i8 * 8 + rr8;
    asrc[i8] = (size_t)(m0 + rloc) * 512 + gseg * 8;
    bsrc[i8] = (size_t)(n0 + rloc) * 512 + gseg * 8;
  }
  f32x4 acc[4][4];
#pragma unroll
  for (int mi = 0; mi < 4; ++mi)
#pragma unroll
    for (int ni = 0; ni < 4; ++ni) {
      f32x4 z = {0.f, 0.f, 0.f, 0.f};
      acc[mi][ni] = z;
    }
#pragma unroll 1
  for (int kc2 = 0; kc2 < 8; ++kc2) {
    int kb = kc2 * 64;
    __syncthreads();
#pragma unroll
    for (int i8 = 0; i8 < 4; ++i8) {
      gload_lds16(A + asrc[i8] + kb, &As[(wave * 32 + i8 * 8) * 64]);
      gload_lds16(Bw + bsrc[i8] + kb, &Bs[(wave * 32 + i8 * 8) * 64]);
    }
    __syncthreads();
#pragma unroll
    for (int h = 0; h < 2; ++h) {
      bf16x8 af[4], bfr[4];
#pragma unroll
      for (int mi = 0; mi < 4; ++mi) {
        int row = wm * 64 + mi * 16 + tq;
        af[mi] = *(const bf16x8*)&As[row * 64 +
                                     ((((h << 2) | quad) ^ (row & 7)) << 3)];
      }
#pragma unroll
      for (int ni = 0; ni < 4; ++ni) {
        int row = wn * 64 + ni * 16 + tq;
        bfr[ni] = *(const bf16x8*)&Bs[row * 64 +
                                      ((((h << 2) | quad) ^ (row & 7)) << 3)];
      }
#pragma unroll
      for (int mi = 0; mi < 4; ++mi)
#pragma unroll
        for (int ni = 0; ni < 4; ++ni)
          acc[mi][ni] = __builtin_amdgcn_mfma_f32_16x16x32_bf16(
              af[mi], bfr[ni], acc[mi][ni], 0, 0, 0);
    }
  }
#pragma unroll
  for (int mi = 0; mi < 4; ++mi)
#pragma unroll
    for (int r = 0; r < 4; ++r) {
      int m = m0 + wm * 64 + mi * 16 + quad * 4 + r;
      size_t obase = (size_t)m * 256 + n0 + wn * 64 + tq;
#pragma unroll
      for (int ni = 0; ni < 4; ++ni) C[obase + ni * 16] = acc[mi][ni][r];
    }
}

// --------------------------- prep (fused) ----------------------------------
// ranges: ea/Wf1/Wf2 casts | wb1 build | wb2 build | x1b halo zeroing
__global__ void prep_all_k(const float* __restrict__ ea,
                           const float* __restrict__ Wf1,
                           const float* __restrict__ Wf2,
                           const float* __restrict__ Wc1,
                           const float* __restrict__ Wc2,
                           unsigned short* __restrict__ eab,
                           unsigned short* __restrict__ wf1b,
                           unsigned short* __restrict__ wf2b,
                           unsigned short* __restrict__ wb1,
                           unsigned short* __restrict__ wb2,
                           unsigned int* __restrict__ x1u) {
  int i = blockIdx.x * 256 + threadIdx.x;
  if (i < 524288) {
    eab[i] = f2bf(ea[i]);
  } else if (i < 1572864) {
    int j = i - 524288;
    wf1b[j] = f2bf(Wf1[j]);
  } else if (i < 1835008) {
    int j = i - 1572864;
    wf2b[j] = f2bf(Wf2[j]);
  } else if (i < 3604480) {
    int j = i - 1835008;  // wb1: [t][kc6][n][72] <- Wc1[n][384][3][3]
    int t = j / (6 * 512 * 64), r = j - t * (6 * 512 * 64);
    int kc = r / (512 * 64), r2 = r - kc * (512 * 64);
    int n = r2 >> 6, c = r2 & 63;
    wb1[((size_t)(t * 6 + kc) * 512 + n) * 72 + c] =
        f2bf(Wc1[(n * 384 + kc * 64 + c) * 9 + t]);
  } else if (i < 5963776) {
    int j = i - 3604480;  // wb2: [t][kc8][n][72] <- Wc2[n][512][3][3]
    int t = j / (8 * 512 * 64), r = j - t * (8 * 512 * 64);
    int kc = r / (512 * 64), r2 = r - kc * (512 * 64);
    int n = r2 >> 6, c = r2 & 63;
    wb2[((size_t)(t * 8 + kc) * 512 + n) * 72 + c] =
        f2bf(Wc2[(n * 512 + kc * 64 + c) * 9 + t]);
  } else {
    int j = i - 5963776;  // 15360 halo rows x 8 slices x 32 uints
    int hr = j >> 8, u = j & 255;
    int slice = u >> 5, uu = u & 31;
    int b = hr / 60, c = hr - b * 60;
    int cell;
    if (c < 16) cell = c;
    else if (c < 32) cell = 240 + (c - 16);
    else if (c < 46) cell = (c - 31) * 16;
    else cell = (c - 45) * 16 + 15;
    x1u[((size_t)slice * RA + b * 256 + cell) * 36 + uu] = 0u;
  }
}

// ev (256,384,14,14) fp32 -> evb [kc6][RA][72] bf16 (halo cells zero)
__global__ __launch_bounds__(256) void evpad_k(const float* __restrict__ ev,
                                               unsigned short* __restrict__ out) {
  int b = blockIdx.x, ct = blockIdx.y;  // channel tile: c0 = ct*64
  __shared__ float tile[64][197];
  int tid = threadIdx.x;
  const float* src = ev + ((size_t)b * 384 + ct * 64) * 196;
#pragma unroll 1
  for (int it = 0; it < 49; ++it) {
    int idx = it * 256 + tid;
    int c = idx / 196, p = idx - c * 196;
    tile[c][p] = src[idx];
  }
  __syncthreads();
  unsigned short* dst = out + ((size_t)ct * RA + b * 256) * 72;
#pragma unroll 1
  for (int it = 0; it < 64; ++it) {
    int idx = it * 256 + tid;
    int cell = idx >> 6, c = idx & 63;
    int h = (cell >> 4) - 1, w = (cell & 15) - 1;
    float v = ((unsigned)h < 14u && (unsigned)w < 14u) ? tile[c][h * 14 + w]
                                                       : 0.f;
    dst[(size_t)cell * 72 + c] = f2bf(v);
  }
}

// --------------------------- pooling / norms -------------------------------

// fused: masked mean pool + per-pixel inverse norm (rn) + ind normalization
__global__ __launch_bounds__(512) void pool_k(
    const unsigned short* __restrict__ fv, const int* __restrict__ masks,
    unsigned short* __restrict__ indnb, unsigned short* __restrict__ ivpb,
    float* __restrict__ Pi, float* __restrict__ rn) {
  int b = blockIdx.x;
  int w = threadIdx.x >> 6, lane = threadIdx.x & 63;
  __shared__ float red[8][512];
  __shared__ float msh[8];
  float acc[8] = {0.f, 0.f, 0.f, 0.f, 0.f, 0.f, 0.f, 0.f};
  float msum = 0.f;
  for (int p = w; p < 196; p += 8) {
    float m = (float)masks[b * 196 + p];
    msum += m;
    uint4 d = *(const uint4*)(fv + (size_t)(b * 196 + p) * 512 + lane * 8);
    const unsigned short* hp = (const unsigned short*)&d;
    float ss = 0.f;
#pragma unroll
    for (int k = 0; k < 8; ++k) {
      float x = bf2f(hp[k]);
      ss += x * x;
      acc[k] += m * x;
    }
    ss = waveSum(ss);
    if (lane == 0) rn[b * 196 + p] = 1.f / fmaxf(sqrtf(ss), 1e-12f);
  }
#pragma unroll
  for (int k = 0; k < 8; ++k) red[w][lane * 8 + k] = acc[k];
  if (lane == 0) msh[w] = msum;
  __syncthreads();
  int tid = threadIdx.x;
  float s = 0.f, mtot = 0.f;
#pragma unroll
  for (int ww = 0; ww < 8; ++ww) {
    s += red[ww][tid];
    mtot += msh[ww];
  }
  float v = s / mtot;  // indv[b, tid]
  float ss2 = blockSum<8>(v * v);
  float sc = 1.f / fmaxf(sqrtf(ss2), 1e-12f);
  indnb[b * 512 + tid] = f2bf(v * sc);
  float ve = v + 1e-6f;
  ivpb[b * 512 + tid] = f2bf(ve);
  float p2 = blockSum<8>(ve * ve);
  if (tid == 0) Pi[b] = p2;
}

// fa fp32 -> bf16 + Qj = ||fa_j||^2
__global__ __launch_bounds__(512) void fanorm_k(const float* __restrict__ fa,
                                                unsigned short* __restrict__ fab,
                                                float* __restrict__ Qj) {
  int b = blockIdx.x, tid = threadIdx.x;
  float v = fa[b * 512 + tid];
  fab[b * 512 + tid] = f2bf(v);
  float q = blockSum<8>(v * v);
  if (tid == 0) Qj[b] = q;
}

// ------------------------------ SP / SN ------------------------------------

__device__ __forceinline__ float radix_kth(unsigned k0, unsigned k1, unsigned k2,
                                           unsigned k3, int k) {
  unsigned prefix = 0;
  int kk = k;
#pragma unroll 1
  for (int bit = 31; bit >= 14; --bit) {  // 18 steps; thr err ~2^-9 rel, ok
    unsigned thi = (prefix >> bit) | 1u;
    int c = __popcll(__ballot((k0 >> bit) == thi)) +
            __popcll(__ballot((k1 >> bit) == thi)) +
            __popcll(__ballot((k2 >> bit) == thi)) +
            __popcll(__ballot((k3 >> bit) == thi));
    if (kk <= c)
      prefix |= (1u << bit);
    else
      kk -= c;
  }
  unsigned u = (prefix & 0x80000000u) ? (prefix ^ 0x80000000u) : ~prefix;
  return __uint_as_float(u);
}
__device__ __forceinline__ unsigned sortkey(float x) {
  unsigned u = __float_as_uint(x);
  return u ^ (((int)u >> 31) | 0x80000000u);
}

__global__ __launch_bounds__(256) void spsn_k(const float* __restrict__ Sij,
                                              float* __restrict__ SP,
                                              float* __restrict__ SN) {
  int i = blockIdx.x, jg = blockIdx.y;
  int tid = threadIdx.x, wave = tid >> 6, lane = tid & 63;
  __shared__ float tile[196 * 65];
#pragma unroll 1
  for (int it = 0; it < 49; ++it) {
    int lin = it * 256 + tid;
    int p = lin >> 6, j = lin & 63;
    tile[p * 65 + j] = Sij[(size_t)(i * 196 + p) * 256 + jg * 64 + j];
  }
  __syncthreads();
#pragma unroll 1
  for (int jj = 0; jj < 16; ++jj) {
    int j = jj * 4 + wave;
    float v0 = tile[lane * 65 + j];
    float v1 = tile[(lane + 64) * 65 + j];
    float v2 = tile[(lane + 128) * 65 + j];
    bool val3 = lane < 4;
    float v3 = val3 ? tile[(lane + 192) * 65 + j] : 0.f;
    unsigned k0 = sortkey(v0), k1 = sortkey(v1), k2 = sortkey(v2);
    unsigned k3 = val3 ? sortkey(v3) : 0u;
    float thrP = radix_kth(k0, k1, k2, k3, 19);
    float thrN = radix_kth(k0, k1, k2, k3, 99);
    float spn = 0.f, spd = 0.f, snn = 0.f, snd = 0.f;
    const float invTS = 1.f / 0.03f;
#pragma unroll
    for (int q = 0; q < 4; ++q) {
      float v = (q == 0) ? v0 : (q == 1) ? v1 : (q == 2) ? v2 : v3;
      bool ok = (q < 3) || val3;
      if (ok) {
        float mp = 1.f / (1.f + __expf((thrP - v) * invTS));
        float mn = 1.f / (1.f + __expf((v - thrN) * invTS));
        spn += v * mp;
        spd += mp;
        snn += v * mn;
        snd += mn;
      }
    }
    spn = waveSum(spn); spd = waveSum(spd);
    snn = waveSum(snn); snd = waveSum(snd);
    if (lane == 0) {
      SP[i * 256 + jg * 64 + j] = spn / spd;
      SN[i * 256 + jg * 64 + j] = snn / snd;
    }
  }
}

__global__ __launch_bounds__(256) void loss12_k(const float* __restrict__ SP,
                                                const float* __restrict__ SN,
                                                float* __restrict__ out) {
  int r = blockIdx.x;
  int i = r & 255;
  bool col = r >= 256;
  int tid = threadIdx.x;
  const float invTC = 1.f / 0.07f;
  float a = (col ? SP[tid * 256 + i] : SP[i * 256 + tid]) * invTC;
  float b = (col ? SN[tid * 256 + i] : SN[i * 256 + tid]) * invTC;
  float mx = blockMax<4>(fmaxf(a, b));
  float se = blockSum<4>(__expf(a - mx) + __expf(b - mx));
  float lse = mx + __logf(se);
  if (tid == 0) {
    float diag = SP[i * 256 + i] * invTC;
    atomicAdd(out, -(diag - lse) * (1.f / 512.f));
  }
}

__global__ __launch_bounds__(256) void distcomb_k(
    const float* __restrict__ Pi, const float* __restrict__ Qj,
    const float* __restrict__ X, const float* __restrict__ V,
    float* __restrict__ val, float* __restrict__ out) {
  int i = blockIdx.x, j = threadIdx.x;
  float d = Pi[i] - 2.f * X[i * 256 + j] + Qj[j];
  float w = (i == j) ? 1.f : -V[i * 256 + j];
  float x = d * w;
  val[i * 256 + j] = x;
  __shared__ float diag_sh;
  if (j == i) diag_sh = x;
  float tot = blockSum<4>(x);
  if (j == 0) {
    float rs = diag_sh - (tot - diag_sh) * (1.f / 255.f);
    atomicAdd(out + 1, fmaxf(rs + 0.6f, 0.f) * (1.f / 512.f));
  }
}

__global__ __launch_bounds__(256) void loss4_k(const float* __restrict__ val,
                                               float* __restrict__ out) {
  int j = blockIdx.x, i = threadIdx.x;
  float x = val[i * 256 + j];
  __shared__ float diag_sh;
  if (i == j) diag_sh = x;
  float tot = blockSum<4>(x);
  if (i == 0) {
    float cs = diag_sh - (tot - diag_sh) * (1.f / 255.f);
    atomicAdd(out + 1, fmaxf(cs + 0.6f, 0.f) * (1.f / 512.f));
  }
}

// ---------------------------------------------------------------------------

extern "C" void kernel_launch(void* const* d_in, const int* in_sizes, int n_in,
                              void* d_out, int out_size, void* d_ws,
                              size_t ws_size, hipStream_t stream) {
  (void)in_sizes; (void)n_in; (void)out_size; (void)ws_size;
  const float* ev = (const float*)d_in[0];
  const float* ea = (const float*)d_in[1];
  const int* msk = (const int*)d_in[2];
  const float* Wf1 = (const float*)d_in[3];
  const float* Wf2 = (const float*)d_in[4];
  const float* Wc1 = (const float*)d_in[5];
  const float* Wc2 = (const float*)d_in[6];
  float* out = (float*)d_out;
  char* ws = (char*)d_ws;

  size_t off = 0;
  auto alloc = [&](size_t bytes) {
    void* p = ws + off;
    off = (off + bytes + 255) & ~(size_t)255;
    return p;
  };
  // Region 1: max(evb 6*RA*144 = 56.6 MB ; fv 50176*512*2 = 51.4 MB)
  unsigned short* evb = (unsigned short*)alloc((size_t)6 * RA * 144);
  unsigned short* fv = evb;  // reused after conv2
  // Region 2: max(x1b 8*RA*144 = 75.5 MB ; Sij 50176*256*4 = 51.4 MB)
  unsigned short* x1b = (unsigned short*)alloc((size_t)8 * RA * 144);
  float* Sij = (float*)x1b;  // reused after conv2
  unsigned short* wb1 = (unsigned short*)alloc((size_t)9 * 6 * 512 * 144);
  unsigned short* wb2 = (unsigned short*)alloc((size_t)9 * 8 * 512 * 144);
  unsigned short* eab = (unsigned short*)alloc((size_t)256 * 2048 * 2);
  unsigned short* wf1b = (unsigned short*)alloc((size_t)512 * 2048 * 2);
  unsigned short* wf2b = (unsigned short*)alloc((size_t)512 * 512 * 2);
  unsigned short* hb = (unsigned short*)alloc((size_t)256 * 512 * 2);
  float* fa = (float*)alloc((size_t)256 * 512 * 4);
  unsigned short* indnb = (unsigned short*)alloc((size_t)256 * 512 * 2);
  unsigned short* ivpb = (unsigned short*)alloc((size_t)256 * 512 * 2);
  unsigned short* fab = (unsigned short*)alloc((size_t)256 * 512 * 2);
  float* Pi = (float*)alloc(256 * 4);
  float* Qj = (float*)alloc(256 * 4);
  float* Xm = (float*)alloc((size_t)256 * 256 * 4);
  float* Vm = (float*)alloc((size_t)256 * 256 * 4);
  float* rn = (float*)alloc((size_t)50176 * 4);
  float* SP = (float*)alloc((size_t)256 * 256 * 4);
  float* SN = (float*)alloc((size_t)256 * 256 * 4);
  float* val = (float*)alloc((size_t)256 * 256 * 4);

  hipMemsetAsync(out, 0, 2 * sizeof(float), stream);

  prep_all_k<<<38656, 256, 0, stream>>>(ea, Wf1, Wf2, Wc1, Wc2, eab, wf1b,
                                        wf2b, wb1, wb2, (unsigned int*)x1b);
  evpad_k<<<dim3(256, 6), 256, 0, stream>>>(ev, evb);

  // conv1: relu, cell rows k-major (one image per block-x, N=512, K=9*384)
  convtap6_k<6, 0><<<dim3(256, 4), 256, 0, stream>>>(evb, wb1, x1b);
  // fc1 / fc2
  gemm1_k<2048, 512, 0><<<dim3(2, 4), 256, 0, stream>>>(eab, wf1b, hb, nullptr);
  gemm1_k<512, 512, 2><<<dim3(2, 4), 256, 0, stream>>>(hb, wf2b, fa, nullptr);
  // conv2: compact bf16 out (one image per block-x, N=512, K=9*512)
  convtap6_k<8, 1><<<dim3(256, 4), 256, 0, stream>>>(x1b, wb2, fv);

  pool_k<<<256, 512, 0, stream>>>(fv, msk, indnb, ivpb, Pi, rn);
  fanorm_k<<<256, 512, 0, stream>>>(fa, fab, Qj);

  // Sij[(i,p), j] = rn[i,p] * <fv[i,p,:], indn[j,:]>  (M=50176, N=256, K=512)
  gemm1_k<512, 256, 3><<<dim3(392, 2), 256, 0, stream>>>(fv, indnb, Sij, rn);
  gemm_xv_k<<<dim3(2, 2, 2), 256, 0, stream>>>(ivpb, fab, indnb, Xm, Vm);

  spsn_k<<<dim3(256, 4), 256, 0, stream>>>(Sij, SP, SN);
  loss12_k<<<512, 256, 0, stream>>>(SP, SN, out);
  distcomb_k<<<256, 256, 0, stream>>>(Pi, Qj, Xm, Vm, val, out);
  loss4_k<<<256, 256, 0, stream>>>(val, out);
}